// Round 7
// baseline (123.399 us; speedup 1.0000x reference)
//
#include <hip/hip_runtime.h>
#include <math.h>

typedef _Float16 half8   __attribute__((ext_vector_type(8)));
typedef _Float16 half4v  __attribute__((ext_vector_type(4)));
typedef float    float4v __attribute__((ext_vector_type(4)));
typedef float    float16v __attribute__((ext_vector_type(16)));

#define BM    64
#define KDIM  256
#define HSW   65    // fp32 h-tile stride: bank = (row+n)%32 -> 2-way (free)

// ---- pre-kernel: W1 fp32 -> fp16 into d_ws (64x256 = 32 KB, L2-resident) ----
__global__ void w1_cvt(const float* __restrict__ W1, _Float16* __restrict__ w1h)
{
    int i = (blockIdx.x * 256 + threadIdx.x) * 4;   // 16 blocks
    float4v v = *(const float4v*)(W1 + i);
    half4v h;
    h[0] = (_Float16)v[0]; h[1] = (_Float16)v[1];
    h[2] = (_Float16)v[2]; h[3] = (_Float16)v[3];
    *(half4v*)(w1h + i) = h;
}

__global__ __launch_bounds__(256, 3)
void qc_fused(const float* __restrict__ x,
              const _Float16* __restrict__ w1h,
              const float* __restrict__ b1,
              const float* __restrict__ W2,
              const float* __restrict__ b2,
              const float* __restrict__ qw,
              float* __restrict__ out)
{
    __shared__ float hs[BM * HSW];    // 16640 B — only LDS the GEMM touches
    __shared__ float angs[BM * 4];
    __shared__ float trig[32];        // [layer][qubit][{cy,sy,cz,sz}] — wave0 only

    const int tid  = threadIdx.x;
    const int lane = tid & 63;
    const int wv   = tid >> 6;
    const int rg   = wv & 1;          // row group: rows rg*32 + n
    const int cg   = wv >> 1;         // col group: cols cg*32 + n
    const int n    = lane & 31;
    const int hg   = lane >> 5;       // k-half: k = hg*8 + j within a 16-step
    const int row0 = blockIdx.x * BM;

    if (tid < 8) {
        int l = tid >> 2, i = tid & 3;
        float wy = qw[(l * 4 + i) * 2 + 0];
        float wz = qw[(l * 4 + i) * 2 + 1];
        float sy, cy, sz, cz;
        sincosf(0.5f * wy, &sy, &cy);
        sincosf(0.5f * wz, &sz, &cz);
        trig[(l * 4 + i) * 4 + 0] = cy;
        trig[(l * 4 + i) * 4 + 1] = sy;
        trig[(l * 4 + i) * 4 + 2] = cz;
        trig[(l * 4 + i) * 4 + 3] = sz;
    }

    // A-operand: A[m=lane&31][k = hg*8 + j]; step s covers k = s*16 .. s*16+15
    const float* xrow = x + (size_t)(row0 + rg * 32 + n) * KDIM + hg * 8;
    // B-operand: B[n=lane&31][k = hg*8 + j] from fp16 W1 (row n of W1 = output col n)
    const _Float16* wrow = w1h + (size_t)(cg * 32 + n) * KDIM + hg * 8;

    // ---- x chunk 0 (steps 0..3): 8 float4 in flight ----
    float4v xv[8];
    #pragma unroll
    for (int s = 0; s < 4; ++s) {
        xv[2 * s]     = *(const float4v*)(xrow + s * 16);
        xv[2 * s + 1] = *(const float4v*)(xrow + s * 16 + 4);
    }

    // ---- W1 fragments: 16 x half8 = 64 VGPRs, held for the whole K-loop ----
    half8 wfr[16];
    #pragma unroll
    for (int s = 0; s < 16; ++s)
        wfr[s] = *(const half8*)(wrow + s * 16);

    const float b1c = b1[cg * 32 + n];   // bias for this lane's output column

    // ---- K-loop: 16 MFMA steps in 4 chunks, loads double-buffered ----
    float16v acc = {};
    half8 af[4];
    #pragma unroll
    for (int c = 0; c < 4; ++c) {
        #pragma unroll
        for (int s = 0; s < 4; ++s) {
            #pragma unroll
            for (int j = 0; j < 4; ++j) {
                af[s][j]     = (_Float16)xv[2 * s][j];
                af[s][4 + j] = (_Float16)xv[2 * s + 1][j];
            }
        }
        if (c < 3) {
            const float* xc = xrow + (c + 1) * 64;   // next 4 steps
            #pragma unroll
            for (int s = 0; s < 4; ++s) {
                xv[2 * s]     = *(const float4v*)(xc + s * 16);
                xv[2 * s + 1] = *(const float4v*)(xc + s * 16 + 4);
            }
        }
        #pragma unroll
        for (int s = 0; s < 4; ++s)
            acc = __builtin_amdgcn_mfma_f32_32x32x16_f16(af[s], wfr[c * 4 + s], acc, 0, 0, 0);
    }

    // ---- bias + relu -> hs; C/D: col = lane&31, row = (reg&3)+8*(reg>>2)+4*hg ----
    {
        const int col = cg * 32 + n;
        #pragma unroll
        for (int reg = 0; reg < 16; ++reg) {
            int row = rg * 32 + (reg & 3) + 8 * (reg >> 2) + 4 * hg;
            hs[row * HSW + col] = fmaxf(acc[reg] + b1c, 0.0f);   // (row+n)%32: 2-way, free
        }
    }
    __syncthreads();

    // ---- GEMM2 + tanh: 256 threads = 64 rows x 4 outputs ----
    {
        int r = tid & 63, qi = tid >> 6;       // qi wave-uniform -> W2/b2 scalar loads
        float s = b2[qi];
        #pragma unroll 8
        for (int k = 0; k < 64; ++k)
            s = fmaf(hs[r * HSW + k], W2[qi * 64 + k], s);   // (r+k)%32: 2-way, free
        angs[r * 4 + qi] = tanhf(s);
    }
    __syncthreads();

    // ---- quantum circuit: one thread per row (wave 0) ----
    if (tid < 64) {
        float ca[4], sa[4];
        #pragma unroll
        for (int i = 0; i < 4; ++i)
            __sincosf(0.5f * angs[tid * 4 + i], &sa[i], &ca[i]);

        // state idx = w0*8 + w1*4 + w2*2 + w3
        float re[16], im[16];
        #pragma unroll
        for (int idx = 0; idx < 16; ++idx) {
            re[idx] = (idx & 8 ? sa[0] : ca[0]) * (idx & 4 ? sa[1] : ca[1]) *
                      (idx & 2 ? sa[2] : ca[2]) * (idx & 1 ? sa[3] : ca[3]);
            im[idx] = 0.0f;
        }
        #pragma unroll
        for (int l = 0; l < 2; ++l) {
            #pragma unroll
            for (int i = 0; i < 4; ++i) {
                const float cy = trig[(l * 4 + i) * 4 + 0];
                const float sy = trig[(l * 4 + i) * 4 + 1];
                const float cz = trig[(l * 4 + i) * 4 + 2];
                const float sz = trig[(l * 4 + i) * 4 + 3];
                const int mq = 8 >> i;
                #pragma unroll
                for (int idx = 0; idx < 16; ++idx) {
                    if (!(idx & mq)) {
                        int j = idx | mq;
                        float ar = re[idx], ai = im[idx], br = re[j], bi = im[j];
                        re[idx] = fmaf(cy, ar, -sy * br);
                        im[idx] = fmaf(cy, ai, -sy * bi);
                        re[j]   = fmaf(sy, ar,  cy * br);
                        im[j]   = fmaf(sy, ai,  cy * bi);
                    }
                }
                #pragma unroll
                for (int idx = 0; idx < 16; ++idx) {
                    float sgn = (idx & mq) ? sz : -sz;
                    float ar = re[idx], ai = im[idx];
                    re[idx] = fmaf(ar, cz, -ai * sgn);
                    im[idx] = fmaf(ar, sgn, ai * cz);
                }
            }
            #pragma unroll
            for (int c = 0; c < 4; ++c) {
                int t  = (c + 1) & 3;
                int mc = 8 >> c, mt = 8 >> t;
                #pragma unroll
                for (int idx = 0; idx < 16; ++idx) {
                    if ((idx & mc) && !(idx & mt)) {
                        int j = idx | mt;
                        float tr = re[idx]; re[idx] = re[j]; re[j] = tr;
                        float ti = im[idx]; im[idx] = im[j]; im[j] = ti;
                    }
                }
            }
        }
        float z = 0.0f;
        #pragma unroll
        for (int idx = 0; idx < 16; ++idx) {
            float p = re[idx] * re[idx] + im[idx] * im[idx];
            z += (idx & 8) ? -p : p;
        }
        out[row0 + tid] = z;
    }
}

extern "C" void kernel_launch(void* const* d_in, const int* in_sizes, int n_in,
                              void* d_out, int out_size, void* d_ws, size_t ws_size,
                              hipStream_t stream) {
    const float* x  = (const float*)d_in[0];
    const float* W1 = (const float*)d_in[1];
    const float* b1 = (const float*)d_in[2];
    const float* W2 = (const float*)d_in[3];
    const float* b2 = (const float*)d_in[4];
    const float* qw = (const float*)d_in[5];
    float* out = (float*)d_out;
    _Float16* w1h = (_Float16*)d_ws;     // 32 KB scratch

    w1_cvt<<<16, 256, 0, stream>>>(W1, w1h);
    const int B = in_sizes[0] / KDIM;    // 65536
    qc_fused<<<B / BM, 256, 0, stream>>>(x, w1h, b1, W2, b2, qw, out);
}